// Round 1
// baseline (28.490 us; speedup 1.0000x reference)
//
#include <hip/hip_runtime.h>
#include <cmath>

#define CC 16      // concepts
#define BB 256     // batch (rows)
#define KK 8       // classes per concept
#define NN 8192    // background size (columns)
#define TPB 1024
#define CHUNK (NN / TPB)     // 8 elements per thread
#define NWAVES (TPB / 64)    // 16 waves per block

__global__ __launch_bounds__(TPB) void beran_kernel(
    const float* __restrict__ c_p,
    const int*   __restrict__ c_in,
    const float* __restrict__ delta_in,
    const float* __restrict__ bandwidth,
    float* __restrict__ out)
{
    constexpr float TOL = 1e-8f + 1e-5f;   // torch.isclose default vs 1.0
    constexpr float EPS = 1e-13f;

    __shared__ float p_lds[CC * KK];   // softmax probs for this row's batch entry
    __shared__ float sq_lds[CC];       // per-concept sum(p^2)
    __shared__ float surv_lds[NN];     // 32 KB: surv values for neighbor access
    __shared__ float wt[NWAVES];       // wave totals for scans/reductions

    const int b    = blockIdx.x;       // one block per batch row
    const int t    = threadIdx.x;
    const int lane = t & 63;
    const int wid  = t >> 6;
    const int n0   = t * CHUNK;        // contiguous chunk per thread

    // ---- per-concept softmax (threads 0..15, one concept each) ----
    if (t < CC) {
        const float* src = c_p + ((size_t)t * BB + b) * KK;
        float v[KK];
        float m = -3.0e38f;
        #pragma unroll
        for (int k = 0; k < KK; ++k) { v[k] = src[k]; m = fmaxf(m, v[k]); }
        float s = 0.f;
        #pragma unroll
        for (int k = 0; k < KK; ++k) { v[k] = __expf(v[k] - m); s += v[k]; }
        float inv = 1.0f / s;
        float ss = 0.f;
        #pragma unroll
        for (int k = 0; k < KK; ++k) {
            float p = v[k] * inv;
            p_lds[t * KK + k] = p;
            ss += p * p;
        }
        sq_lds[t] = ss;
    }
    __syncthreads();

    // S = sum_c sumsq[c] + C   (metric = S - 2*sum_c p[c,label])
    float S = (float)CC;
    #pragma unroll
    for (int c = 0; c < CC; ++c) S += sq_lds[c];
    const float bw = fminf(fmaxf(bandwidth[0], 0.1f), 10.0f);
    const float inv_bw = 1.0f / bw;

    // ---- pass A: raw kernel weights (registers) ----
    float w[CHUNK];
    #pragma unroll
    for (int i = 0; i < CHUNK; ++i) {
        const int n = n0 + i;
        const int4* row = (const int4*)(c_in + (size_t)n * CC);
        int4 q0 = row[0], q1 = row[1], q2 = row[2], q3 = row[3];
        float dot =
            p_lds[ 0*KK + q0.x] + p_lds[ 1*KK + q0.y] + p_lds[ 2*KK + q0.z] + p_lds[ 3*KK + q0.w] +
            p_lds[ 4*KK + q1.x] + p_lds[ 5*KK + q1.y] + p_lds[ 6*KK + q1.z] + p_lds[ 7*KK + q1.w] +
            p_lds[ 8*KK + q2.x] + p_lds[ 9*KK + q2.y] + p_lds[10*KK + q2.z] + p_lds[11*KK + q2.w] +
            p_lds[12*KK + q3.x] + p_lds[13*KK + q3.y] + p_lds[14*KK + q3.z] + p_lds[15*KK + q3.w];
        w[i] = __expf((2.0f * dot - S) * inv_bw);
    }

    // ---- scan 1: inclusive cumsum of raw weights ----
    float incl[CHUNK];
    float run = 0.f;
    #pragma unroll
    for (int i = 0; i < CHUNK; ++i) { run += w[i]; incl[i] = run; }
    float x = run;
    #pragma unroll
    for (int d = 1; d < 64; d <<= 1) {
        float y = __shfl_up(x, d);
        if (lane >= d) x += y;
    }
    if (lane == 63) wt[wid] = x;
    __syncthreads();
    float woff = 0.f, total = 0.f;
    #pragma unroll
    for (int ww = 0; ww < NWAVES; ++ww) {
        float v = wt[ww];
        if (ww < wid) woff += v;
        total += v;
    }
    const float base1 = woff + (x - run);           // exclusive offset for this thread
    const float inv_s = (total < EPS) ? 0.0f : (1.0f / total);

    // ---- xi (normalized on the fly: cs = cumsum_raw/total so last element
    //      is 1 within a few ulp -> isclose mask fires like the reference) ----
    float4 dl0 = *(const float4*)(delta_in + n0);
    float4 dl1 = *(const float4*)(delta_in + n0 + 4);
    const float del[CHUNK] = {dl0.x, dl0.y, dl0.z, dl0.w, dl1.x, dl1.y, dl1.z, dl1.w};
    float fxi[CHUNK];
    #pragma unroll
    for (int i = 0; i < CHUNK; ++i) {
        float cs = (base1 + incl[i]) * inv_s;       // inclusive cumsum of W
        float Wn = w[i] * inv_s;                    // W[n]
        float sh = cs - Wn;                         // exclusive cumsum (shifted)
        bool bad = (fabsf(sh - 1.0f) <= TOL) || (fabsf(cs - 1.0f) <= TOL);
        float xi = bad ? 0.0f : (__logf(1.0f - sh) - __logf(1.0f - cs));
        fxi[i] = del[i] * xi;
    }

    // ---- scan 2: hazards = cumsum(filtered_xi) ----
    run = 0.f;
    #pragma unroll
    for (int i = 0; i < CHUNK; ++i) { run += fxi[i]; incl[i] = run; }
    x = run;
    #pragma unroll
    for (int d = 1; d < 64; d <<= 1) {
        float y = __shfl_up(x, d);
        if (lane >= d) x += y;
    }
    __syncthreads();               // all scan-1 reads of wt[] complete
    if (lane == 63) wt[wid] = x;
    __syncthreads();
    woff = 0.f;
    #pragma unroll
    for (int ww = 0; ww < NWAVES; ++ww) {
        float v = wt[ww];
        if (ww < wid) woff += v;
    }
    const float base2 = woff + (x - run);

    // ---- surv_func = exp(-hazards) ----
    float* out0 = out + (size_t)b * NN;
    float sv[CHUNK];
    #pragma unroll
    for (int i = 0; i < CHUNK; ++i) sv[i] = __expf(-(base2 + incl[i]));
    *(float4*)(surv_lds + n0)     = make_float4(sv[0], sv[1], sv[2], sv[3]);
    *(float4*)(surv_lds + n0 + 4) = make_float4(sv[4], sv[5], sv[6], sv[7]);
    *(float4*)(out0 + n0)         = make_float4(sv[0], sv[1], sv[2], sv[3]);
    *(float4*)(out0 + n0 + 4)     = make_float4(sv[4], sv[5], sv[6], sv[7]);
    __syncthreads();

    // ---- surv_steps ----
    float prev = (t == 0) ? 1.0f : surv_lds[n0 - 1];
    float st[CHUNK];
    float ls = 0.f;
    #pragma unroll
    for (int i = 0; i < CHUNK; ++i) {
        st[i] = prev - sv[i];      // steps[0] = 1 - surv[0]; steps[n] = surv[n-1]-surv[n]
        prev = sv[i];
        ls += st[i];
    }
    x = ls;
    #pragma unroll
    for (int d = 1; d < 64; d <<= 1) x += __shfl_xor(x, d);
    if (lane == 0) wt[wid] = x;    // safe: scan-2 reads of wt[] were before last barrier
    __syncthreads();
    float s2 = 0.f;
    #pragma unroll
    for (int ww = 0; ww < NWAVES; ++ww) s2 += wt[ww];
    const float inv2 = (s2 < EPS) ? 0.0f : (1.0f / s2);
    float* out1 = out + (size_t)BB * NN + (size_t)b * NN;
    *(float4*)(out1 + n0)     = make_float4(st[0]*inv2, st[1]*inv2, st[2]*inv2, st[3]*inv2);
    *(float4*)(out1 + n0 + 4) = make_float4(st[4]*inv2, st[5]*inv2, st[6]*inv2, st[7]*inv2);
}

extern "C" void kernel_launch(void* const* d_in, const int* in_sizes, int n_in,
                              void* d_out, int out_size, void* d_ws, size_t ws_size,
                              hipStream_t stream) {
    (void)in_sizes; (void)n_in; (void)out_size; (void)d_ws; (void)ws_size;
    const float* c_p       = (const float*)d_in[0];
    const int*   c_in      = (const int*)d_in[1];
    const float* delta_in  = (const float*)d_in[2];
    const float* bandwidth = (const float*)d_in[3];
    float*       out       = (float*)d_out;
    hipLaunchKernelGGL(beran_kernel, dim3(BB), dim3(TPB), 0, stream,
                       c_p, c_in, delta_in, bandwidth, out);
}

// Round 2
// 21.626 us; speedup vs baseline: 1.3174x; 1.3174x over previous
//
#include <hip/hip_runtime.h>
#include <cmath>

#define CC 16      // concepts
#define BB 256     // batch (rows)
#define KK 8       // classes per concept
#define NN 8192    // background size (columns)
#define TPB 1024
#define CHUNK (NN / TPB)     // 8 elements per thread
#define NWAVES (TPB / 64)    // 16 waves per block

__global__ __launch_bounds__(TPB) void beran_kernel(
    const float* __restrict__ c_p,
    const int*   __restrict__ c_in,
    const float* __restrict__ delta_in,
    const float* __restrict__ bandwidth,
    float* __restrict__ out)
{
    constexpr float TOL = 1e-8f + 1e-5f;   // torch.isclose default vs 1.0
    constexpr float EPS = 1e-13f;

    __shared__ float p_lds[CC * KK];       // softmax probs for this batch row
    __shared__ float sq_lds[CC];           // per-concept sum(p^2)
    __shared__ float w_lds[NN + NN / 8];   // 36 KB padded transpose buffer
    __shared__ float wt[NWAVES];           // wave totals, scan 1 (+ steps reduce later)
    __shared__ float wt2[NWAVES];          // wave totals, scan 2
    __shared__ float wl[NWAVES];           // per-wave last surv value

    const int b    = blockIdx.x;           // one block per batch row
    const int t    = threadIdx.x;
    const int lane = t & 63;
    const int wid  = t >> 6;
    const int n0   = t * CHUNK;            // contiguous chunk (scan phases)

    // ---- per-concept softmax (threads 0..15, one concept each) ----
    if (t < CC) {
        const float* src = c_p + ((size_t)t * BB + b) * KK;
        float v[KK];
        float m = -3.0e38f;
        #pragma unroll
        for (int k = 0; k < KK; ++k) { v[k] = src[k]; m = fmaxf(m, v[k]); }
        float s = 0.f;
        #pragma unroll
        for (int k = 0; k < KK; ++k) { v[k] = __expf(v[k] - m); s += v[k]; }
        float inv = 1.0f / s;
        float ss = 0.f;
        #pragma unroll
        for (int k = 0; k < KK; ++k) {
            float p = v[k] * inv;
            p_lds[t * KK + k] = p;
            ss += p * p;
        }
        sq_lds[t] = ss;
    }
    __syncthreads();

    // S = sum_c sumsq[c] + C   (metric = S - 2*sum_c p[c,label])
    float S = (float)CC;
    #pragma unroll
    for (int c = 0; c < CC; ++c) S += sq_lds[c];
    const float bw = fminf(fmaxf(bandwidth[0], 0.1f), 10.0f);
    const float inv_bw = 1.0f / bw;

    // ---- pass A (STRIDED n = k*TPB + t): coalesced c_in reads ----
    // Each wave's 4 int4 loads cover one contiguous 4KB span (1 line-touch/line).
    #pragma unroll
    for (int k = 0; k < CHUNK; ++k) {
        const int n = k * TPB + t;
        const int4* row = (const int4*)(c_in + (size_t)n * CC);
        int4 q0 = row[0], q1 = row[1], q2 = row[2], q3 = row[3];
        float dot =
            p_lds[ 0*KK + q0.x] + p_lds[ 1*KK + q0.y] + p_lds[ 2*KK + q0.z] + p_lds[ 3*KK + q0.w] +
            p_lds[ 4*KK + q1.x] + p_lds[ 5*KK + q1.y] + p_lds[ 6*KK + q1.z] + p_lds[ 7*KK + q1.w] +
            p_lds[ 8*KK + q2.x] + p_lds[ 9*KK + q2.y] + p_lds[10*KK + q2.z] + p_lds[11*KK + q2.w] +
            p_lds[12*KK + q3.x] + p_lds[13*KK + q3.y] + p_lds[14*KK + q3.z] + p_lds[15*KK + q3.w];
        // padded transpose store: idx(n) = n + (n>>3); banks <= 4-way
        w_lds[n + (n >> 3)] = __expf((2.0f * dot - S) * inv_bw);
    }
    __syncthreads();

    // ---- transpose read back (chunked): idx(t*8+i) = 9*t + i; 2-way banks ----
    float w[CHUNK];
    #pragma unroll
    for (int i = 0; i < CHUNK; ++i) w[i] = w_lds[9 * t + i];

    // ---- scan 1: inclusive cumsum of raw weights ----
    float incl[CHUNK];
    float run = 0.f;
    #pragma unroll
    for (int i = 0; i < CHUNK; ++i) { run += w[i]; incl[i] = run; }
    float x = run;
    #pragma unroll
    for (int d = 1; d < 64; d <<= 1) {
        float y = __shfl_up(x, d);
        if (lane >= d) x += y;
    }
    if (lane == 63) wt[wid] = x;
    __syncthreads();
    float woff = 0.f, total = 0.f;
    #pragma unroll
    for (int ww = 0; ww < NWAVES; ++ww) {
        float v = wt[ww];
        if (ww < wid) woff += v;
        total += v;
    }
    const float base1 = woff + (x - run);           // exclusive offset for this thread
    const float inv_s = (total < EPS) ? 0.0f : (1.0f / total);

    // ---- xi (cs = cumsum_raw/total; last element -> 1 within ulp so the
    //      isclose mask fires at the tail exactly like the reference) ----
    float4 dl0 = *(const float4*)(delta_in + n0);
    float4 dl1 = *(const float4*)(delta_in + n0 + 4);
    const float del[CHUNK] = {dl0.x, dl0.y, dl0.z, dl0.w, dl1.x, dl1.y, dl1.z, dl1.w};
    float fxi[CHUNK];
    #pragma unroll
    for (int i = 0; i < CHUNK; ++i) {
        float cs = (base1 + incl[i]) * inv_s;       // inclusive cumsum of W
        float Wn = w[i] * inv_s;                    // W[n]
        float sh = cs - Wn;                         // exclusive cumsum (shifted)
        bool bad = (fabsf(sh - 1.0f) <= TOL) || (fabsf(cs - 1.0f) <= TOL);
        float xi = bad ? 0.0f : (__logf(1.0f - sh) - __logf(1.0f - cs));
        fxi[i] = del[i] * xi;
    }

    // ---- scan 2: hazards = cumsum(filtered_xi) ----
    run = 0.f;
    #pragma unroll
    for (int i = 0; i < CHUNK; ++i) { run += fxi[i]; incl[i] = run; }
    x = run;
    #pragma unroll
    for (int d = 1; d < 64; d <<= 1) {
        float y = __shfl_up(x, d);
        if (lane >= d) x += y;
    }
    if (lane == 63) wt2[wid] = x;
    __syncthreads();
    woff = 0.f;
    #pragma unroll
    for (int ww = 0; ww < NWAVES; ++ww) {
        float v = wt2[ww];
        if (ww < wid) woff += v;
    }
    const float base2 = woff + (x - run);

    // ---- surv_func = exp(-hazards) ----
    float* out0 = out + (size_t)b * NN;
    float sv[CHUNK];
    #pragma unroll
    for (int i = 0; i < CHUNK; ++i) sv[i] = __expf(-(base2 + incl[i]));
    *(float4*)(out0 + n0)     = make_float4(sv[0], sv[1], sv[2], sv[3]);
    *(float4*)(out0 + n0 + 4) = make_float4(sv[4], sv[5], sv[6], sv[7]);
    if (lane == 63) wl[wid] = sv[CHUNK - 1];        // wave-boundary surv
    __syncthreads();

    // ---- surv_steps: neighbor surv[n0-1] via shfl + wave boundary ----
    float pv = __shfl_up(sv[CHUNK - 1], 1);         // prev thread's last surv
    if (lane == 0) pv = (wid == 0) ? 1.0f : wl[wid - 1];
    if (t == 0)    pv = 1.0f;
    float st[CHUNK];
    float ls = 0.f;
    #pragma unroll
    for (int i = 0; i < CHUNK; ++i) {
        st[i] = pv - sv[i];        // steps[0]=1-surv[0]; steps[n]=surv[n-1]-surv[n]
        pv = sv[i];
        ls += st[i];
    }
    x = ls;
    #pragma unroll
    for (int d = 1; d < 64; d <<= 1) x += __shfl_xor(x, d);
    if (lane == 0) wt[wid] = x;    // wt reads finished before the prior barriers
    __syncthreads();
    float s2 = 0.f;
    #pragma unroll
    for (int ww = 0; ww < NWAVES; ++ww) s2 += wt[ww];
    const float inv2 = (s2 < EPS) ? 0.0f : (1.0f / s2);
    float* out1 = out + (size_t)BB * NN + (size_t)b * NN;
    *(float4*)(out1 + n0)     = make_float4(st[0]*inv2, st[1]*inv2, st[2]*inv2, st[3]*inv2);
    *(float4*)(out1 + n0 + 4) = make_float4(st[4]*inv2, st[5]*inv2, st[6]*inv2, st[7]*inv2);
}

extern "C" void kernel_launch(void* const* d_in, const int* in_sizes, int n_in,
                              void* d_out, int out_size, void* d_ws, size_t ws_size,
                              hipStream_t stream) {
    (void)in_sizes; (void)n_in; (void)out_size; (void)d_ws; (void)ws_size;
    const float* c_p       = (const float*)d_in[0];
    const int*   c_in      = (const int*)d_in[1];
    const float* delta_in  = (const float*)d_in[2];
    const float* bandwidth = (const float*)d_in[3];
    float*       out       = (float*)d_out;
    hipLaunchKernelGGL(beran_kernel, dim3(BB), dim3(TPB), 0, stream,
                       c_p, c_in, delta_in, bandwidth, out);
}